// Round 12
// baseline (98.425 us; speedup 1.0000x reference)
//
#include <hip/hip_runtime.h>
#include <hip/hip_bf16.h>
#include <stdint.h>

// MinGRU: B=8, S=4096, I=512, H=512 (fp32 in/out)
// R11: R10's 8-phase 256^2 GEMM + coalesced epilogue: gate output staged in
//      LDS (256x128 uint, stride 136) after the K-loop, then written to ab
//      as 512B-contiguous uint4 rows (was 64B-granule scatter => ~2x HBM
//      write amplification, the actual binding constraint since R5).

typedef __attribute__((ext_vector_type(8))) short short8;   // 8 bf16
typedef __attribute__((ext_vector_type(4))) float f32x4;

#define AS1 __attribute__((address_space(1)))
#define AS3 __attribute__((address_space(3)))

__device__ inline void gload_lds16(const void* g, void* l) {
  __builtin_amdgcn_global_load_lds((AS1 uint32_t*)(g), (AS3 uint32_t*)(l), 16, 0, 0);
}

__device__ inline ushort f2bf(float f) {
  union { __hip_bfloat16 h; ushort u; } v;
  v.h = __float2bfloat16(f);
  return v.u;
}

// ---------------- K0: fp32 -> bf16; also builds interleaved Wcat ------------
// Wcat[1024,512]: row r: g=r>>6, q=r&63; q<32 -> Wz[g*32+q], else Wh[g*32+q-32].
__global__ void cvt_all(const float* __restrict__ x,
                        const float* __restrict__ wz,
                        const float* __restrict__ wh,
                        ushort* __restrict__ xb,
                        ushort* __restrict__ wcat) {
  int i = blockIdx.x * 256 + threadIdx.x;
  for (; i < 4325376; i += 2048 * 256) {
    if (i < 4194304) {
      float4 v = reinterpret_cast<const float4*>(x)[i];
      reinterpret_cast<ushort4*>(xb)[i] =
          make_ushort4(f2bf(v.x), f2bf(v.y), f2bf(v.z), f2bf(v.w));
    } else {
      int j = i - 4194304;             // float4 index into wcat [1024][128]
      int row = j >> 7, c4 = j & 127;
      int g = row >> 6, q = row & 63;
      const float* src = (q < 32) ? (wz + (size_t)(g * 32 + q) * 512)
                                  : (wh + (size_t)(g * 32 + q - 32) * 512);
      float4 v = reinterpret_cast<const float4*>(src)[c4];
      reinterpret_cast<ushort4*>(wcat)[j] =
          make_ushort4(f2bf(v.x), f2bf(v.y), f2bf(v.z), f2bf(v.w));
    }
  }
}

// ---------------- K1: 8-phase 256^2 GEMM + gate + chunk summaries ----------
// grid 512 (XCD-chunked bijective): tile=(bid&7)*64+(bid>>3); mt=tile>>2,
// nt=tile&3. 8 waves 2Mx4N: wave = 128 rows x 64 cols.
// K-loop LDS (128K): buf0A[0,32K) buf0B[32K,64K) buf1A[64K,96K) buf1B[96K,128K)
// tile=[256 rows][64 bf16=128B rows, 8 slots], swizzle slot ^= row&7.
// Epilogue LDS (reuse, 139264B): uint stage[256][136] -> coalesced ab writes.
__global__ __launch_bounds__(512, 2) void gemm_gate(
    const ushort* __restrict__ xb,    // [32768,512] bf16
    const ushort* __restrict__ wcat,  // [1024,512] bf16 interleaved
    const float* __restrict__ b_z,
    const float* __restrict__ b_h,
    uint* __restrict__ ab,            // [32768,512] packed (a,b) bf16
    float2* __restrict__ ABc)         // [8,512,128] chunk summaries (b,h,c)
{
  __shared__ __align__(16) char smem[139264];

  const int t  = threadIdx.x;
  const int w  = t >> 6;              // wave 0..7
  const int l  = t & 63;
  const int lm = l & 15;
  const int lk = l >> 4;
  const int wm = w >> 2;              // 0..1  (row half)
  const int wn = w & 3;               // 0..3  (64-col group)

  const int bid  = blockIdx.x;
  const int tile = (bid & 7) * 64 + (bid >> 3);   // bijective, 512 % 8 == 0
  const int mt = tile >> 2;           // 0..127
  const int nt = tile & 3;            // 0..3
  const int m0 = mt * 256;
  const int n0 = nt * 256;            // within 1024-wide Wcat rows

  const int sr8 = l >> 3;             // 0..7 (staging row within wave)
  const int gs  = (l & 7) ^ sr8;      // swizzled 16B slot on the GLOBAL side

  enum { B0A = 0, B0B = 32768, B1A = 65536, B1B = 98304 };

  f32x4 acc[8][4];
  #pragma unroll
  for (int m = 0; m < 8; ++m)
    #pragma unroll
    for (int nf = 0; nf < 4; ++nf)
      acc[m][nf] = (f32x4){0.f, 0.f, 0.f, 0.f};

  auto stageA = [&](int region, int kt, int half) {
    #pragma unroll
    for (int j = 0; j < 2; ++j) {
      int row = half * 128 + j * 64 + w * 8 + sr8;
      gload_lds16(xb + (size_t)(m0 + row) * 512 + kt * 64 + gs * 8,
                  smem + region + (half * 128 + j * 64) * 128 + w * 1024);
    }
  };
  auto stageB = [&](int region, int kt, int half) {
    #pragma unroll
    for (int j = 0; j < 2; ++j) {
      int row = half * 128 + j * 64 + w * 8 + sr8;
      gload_lds16(wcat + (size_t)(n0 + row) * 512 + kt * 64 + gs * 8,
                  smem + region + (half * 128 + j * 64) * 128 + w * 1024);
    }
  };

  short8 aF[2][2], bB[4][2];          // A per-phase, B per-K-tile (held 4 ph)

#define RD_A(BUFA, MQ)                                                        \
  _Pragma("unroll") for (int mm = 0; mm < 2; ++mm)                            \
  _Pragma("unroll") for (int ks = 0; ks < 2; ++ks) {                          \
    int row = wm * 128 + (2 * (MQ) + mm) * 16 + lm;                           \
    aF[mm][ks] = *(const short8*)(smem + (BUFA) + row * 128 +                 \
                                  (((ks * 4 + lk) ^ (lm & 7)) << 4));         \
  }

#define RD_B(BUFB)                                                            \
  _Pragma("unroll") for (int nf = 0; nf < 4; ++nf)                            \
  _Pragma("unroll") for (int ks = 0; ks < 2; ++ks) {                          \
    int row = wn * 64 + nf * 16 + lm;                                         \
    bB[nf][ks] = *(const short8*)(smem + (BUFB) + row * 128 +                 \
                                  (((ks * 4 + lk) ^ (lm & 7)) << 4));         \
  }

#define PHASE(BUFA, BUFB, MQ, READB, STAGE, VMN)                              \
  {                                                                           \
    if (READB) { RD_B(BUFB); }                                                \
    RD_A(BUFA, MQ);                                                           \
    STAGE;                                                                    \
    if ((VMN) == 4)      asm volatile("s_waitcnt vmcnt(4)" ::: "memory");     \
    else if ((VMN) == 0) asm volatile("s_waitcnt vmcnt(0)" ::: "memory");     \
    __builtin_amdgcn_s_barrier();                                             \
    asm volatile("s_waitcnt lgkmcnt(0)" ::: "memory");                        \
    __builtin_amdgcn_sched_barrier(0);                                        \
    __builtin_amdgcn_s_setprio(1);                                            \
    _Pragma("unroll") for (int ks = 0; ks < 2; ++ks)                          \
    _Pragma("unroll") for (int nf = 0; nf < 4; ++nf) {                        \
      acc[2 * (MQ)][nf]     = __builtin_amdgcn_mfma_f32_16x16x32_bf16(        \
          aF[0][ks], bB[nf][ks], acc[2 * (MQ)][nf], 0, 0, 0);                 \
      acc[2 * (MQ) + 1][nf] = __builtin_amdgcn_mfma_f32_16x16x32_bf16(        \
          aF[1][ks], bB[nf][ks], acc[2 * (MQ) + 1][nf], 0, 0, 0);             \
    }                                                                         \
    __builtin_amdgcn_s_setprio(0);                                            \
    __builtin_amdgcn_s_barrier();                                             \
  }

  // prologue: A(0),B(0) -> buf0; B(1) -> buf1B; wait all but B(1)
  stageA(B0A, 0, 0); stageA(B0A, 0, 1);
  stageB(B0B, 0, 0); stageB(B0B, 0, 1);
  stageB(B1B, 1, 0); stageB(B1B, 1, 1);
  asm volatile("s_waitcnt vmcnt(4)" ::: "memory");
  __builtin_amdgcn_s_barrier();

  // K = 512 -> 8 K-tiles of 64 -> 4 iters x (even ktile buf0, odd ktile buf1)
  #pragma unroll
  for (int it = 0; it < 4; ++it) {
    const int ko = 2 * it + 1, ke2 = 2 * it + 2, ko2 = 2 * it + 3;
    PHASE(B0A, B0B, 0, true,  { stageA(B1A, ko, 0); },               -1)
    PHASE(B0A, B0B, 1, false, { stageA(B1A, ko, 1); },               -1)
    PHASE(B0A, B0B, 2, false, { if (it < 3) stageB(B0B, ke2, 0); },  -1)
    PHASE(B0A, B0B, 3, false, { if (it < 3) stageB(B0B, ke2, 1); },  (it < 3) ? 4 : 0)
    PHASE(B1A, B1B, 0, true,  { if (it < 3) stageA(B0A, ke2, 0); },  -1)
    PHASE(B1A, B1B, 1, false, { if (it < 3) stageA(B0A, ke2, 1); },  -1)
    PHASE(B1A, B1B, 2, false, { if (it < 3) stageB(B1B, ko2, 0); },  -1)
    PHASE(B1A, B1B, 3, false, { if (it < 3) stageB(B1B, ko2, 1); },  (it < 3) ? 4 : 0)
  }
#undef PHASE
#undef RD_A
#undef RD_B

  // ---- gate epilogue: compute (a,b), stage packed uints in LDS, ----
  // ---- fused chunk summaries (unchanged math). ----
  // C frag layout (16x16): col = lm, row = lk*4 + j. Wave cols = one 64-col
  // group g = nt*4 + wn: nf 0,1 = z of h-channels g*32+{0..31}; nf 2,3 = h~.
  uint* stg = (uint*)smem;                          // [256][136]
  const int g    = nt * 4 + wn;
  const int bidx = mt >> 4;                         // batch
  #pragma unroll
  for (int gp = 0; gp < 2; ++gp) {
    const int h    = g * 32 + gp * 16 + lm;         // global h (0..511)
    const int hloc = wn * 32 + gp * 16 + lm;        // block-local col (0..127)
    const float bz = b_z[h], bh = b_h[h];
    #pragma unroll
    for (int cb = 0; cb < 4; ++cb) {                // chunk = 32 rows = 2 frags
      float cA = 1.f, cB = 0.f;
      #pragma unroll
      for (int mm = 0; mm < 2; ++mm) {
        const int m = 2 * cb + mm;
        float sA = 1.f, sB = 0.f;
        #pragma unroll
        for (int j = 0; j < 4; ++j) {
          float uz = acc[m][gp][j] + bz;
          float uh = acc[m][gp + 2][j] + bh;
          float z  = 1.f / (1.f + __expf(-uz));
          float a  = 1.f - z;
          float bb = z * uh;
          int rloc = wm * 128 + m * 16 + lk * 4 + j;
          stg[rloc * 136 + hloc] = (uint)f2bf(a) | ((uint)f2bf(bb) << 16);
          sA = a * sA;
          sB = a * sB + bb;                         // j asc = time asc
        }
        float Ag = 1.f, Bg = 0.f;
        #pragma unroll
        for (int q = 0; q < 4; ++q) {               // lk-segments, time order
          float Aq = __shfl(sA, q * 16 + lm);
          float Bq = __shfl(sB, q * 16 + lm);
          Ag = Aq * Ag;
          Bg = Aq * Bg + Bq;
        }
        cB = Ag * cB + Bg;                          // mm asc = time asc
        cA = Ag * cA;
      }
      if (lk == 0) {
        int c = (mt & 15) * 8 + wm * 4 + cb;        // chunk within batch
        ABc[((size_t)bidx * 512 + h) * 128 + c] = make_float2(cA, cB);
      }
    }
  }
  __syncthreads();

  // ---- coalesced writeback: 512B-contiguous uint4 rows ----
  {
    const int rr = t >> 5;            // 0..15
    const int q  = t & 31;            // uint4 within row
    #pragma unroll
    for (int it2 = 0; it2 < 16; ++it2) {
      int row = it2 * 16 + rr;
      uint4 v = *(const uint4*)(stg + row * 136 + q * 4);
      *(uint4*)(ab + (size_t)(m0 + row) * 512 + nt * 128 + q * 4) = v;
    }
  }
}

// ---------------- K3: wave-parallel scan over chunk summaries ----------------
__global__ __launch_bounds__(256) void chunk_scan(
    const float2* __restrict__ ABc,   // [8,512,128]
    const float* __restrict__ h0,
    float* __restrict__ Hinit)        // [8,128,512]
{
  __shared__ float sm[128][4];
  const int w = threadIdx.x >> 6, l = threadIdx.x & 63;
  const int b   = blockIdx.x >> 7;
  const int h0g = (blockIdx.x & 127) * 4;
  const int h   = h0g + w;

  const float2* base = ABc + ((size_t)b * 512 + h) * 128;
  float2 s1 = base[l];
  float2 s2 = base[64 + l];

  float A1 = s1.x, B1 = s1.y;
  #pragma unroll
  for (int d = 1; d < 64; d <<= 1) {
    float uA = __shfl_up(A1, d);
    float uB = __shfl_up(B1, d);
    if (l >= d) { B1 = A1 * uB + B1; A1 = A1 * uA; }
  }
  float A2 = s2.x, B2 = s2.y;
  #pragma unroll
  for (int d = 1; d < 64; d <<= 1) {
    float uA = __shfl_up(A2, d);
    float uB = __shfl_up(B2, d);
    if (l >= d) { B2 = A2 * uB + B2; A2 = A2 * uA; }
  }
  float PA = __shfl(A1, 63), PB = __shfl(B1, 63);   // prefix of chunks 0..63
  float FA = A2 * PA;
  float FB = A2 * PB + B2;

  float e1A = __shfl_up(A1, 1), e1B = __shfl_up(B1, 1);
  if (l == 0) { e1A = 1.f; e1B = 0.f; }
  float e2A = __shfl_up(FA, 1), e2B = __shfl_up(FB, 1);
  if (l == 0) { e2A = PA; e2B = PB; }

  float h0v = h0[b * 512 + h];
  sm[l][w]      = e1A * h0v + e1B;
  sm[64 + l][w] = e2A * h0v + e2B;
  __syncthreads();

  const int tt = threadIdx.x;
  if (tt < 128) {
    float4 v = *(const float4*)sm[tt];
    *(float4*)(Hinit + ((size_t)b * 128 + tt) * 512 + h0g) = v;
  }
}

// ---------------- K4: replay each chunk from Hinit, write out ----------------
__global__ __launch_bounds__(256) void scan_write(
    const uint* __restrict__ ab,
    const float* __restrict__ Hinit,
    float* __restrict__ out)
{
  int tid = blockIdx.x * 256 + threadIdx.x;   // 131072
  int cg = tid & 127;            // h-group: h = cg*4 ..
  int c  = (tid >> 7) & 127;
  int b  = tid >> 14;
  const uint4* p = reinterpret_cast<const uint4*>(ab + ((size_t)(b * 4096 + c * 32)) * 512) + cg;
  float4 hv = *reinterpret_cast<const float4*>(Hinit + ((size_t)b * 128 + c) * 512 + cg * 4);
  float4* po = reinterpret_cast<float4*>(out + ((size_t)(b * 4096 + c * 32)) * 512) + cg;
  #pragma unroll 4
  for (int t = 0; t < 32; ++t) {
    uint4 u = p[(size_t)t * 128];
    hv.x = __uint_as_float(u.x << 16) * hv.x + __uint_as_float(u.x & 0xffff0000u);
    hv.y = __uint_as_float(u.y << 16) * hv.y + __uint_as_float(u.y & 0xffff0000u);
    hv.z = __uint_as_float(u.z << 16) * hv.z + __uint_as_float(u.z & 0xffff0000u);
    hv.w = __uint_as_float(u.w << 16) * hv.w + __uint_as_float(u.w & 0xffff0000u);
    po[(size_t)t * 128] = hv;
  }
}

extern "C" void kernel_launch(void* const* d_in, const int* in_sizes, int n_in,
                              void* d_out, int out_size, void* d_ws, size_t ws_size,
                              hipStream_t stream) {
  const float* x   = (const float*)d_in[0];
  const float* h0  = (const float*)d_in[1];
  const float* W_z = (const float*)d_in[2];
  const float* b_z = (const float*)d_in[3];
  const float* W_h = (const float*)d_in[4];
  const float* b_h = (const float*)d_in[5];
  float* out = (float*)d_out;

  char* ws = (char*)d_ws;
  ushort* xb    = (ushort*)(ws);                  // 33,554,432 B
  ushort* wcat  = (ushort*)(ws + 33554432);       //  1,048,576 B [1024,512]
  uint*   ab    = (uint*)  (ws + 34603008);       // 67,108,864 B
  float2* ABc   = (float2*)(ws + 101711872);      //  4,194,304 B  [8,512,128]
  float*  Hinit = (float*) (ws + 105906176);      //  2,097,152 B  [8,128,512]

  cvt_all<<<2048, 256, 0, stream>>>(x, W_z, W_h, xb, wcat);
  gemm_gate<<<512, 512, 0, stream>>>(xb, wcat, b_z, b_h, ab, ABc);
  chunk_scan<<<1024, 256, 0, stream>>>(ABc, h0, Hinit);
  scan_write<<<512, 256, 0, stream>>>(ab, Hinit, out);
}

// Round 13
// 91.686 us; speedup vs baseline: 1.0735x; 1.0735x over previous
//
#include <hip/hip_runtime.h>
#include <hip/hip_bf16.h>
#include <stdint.h>

// MinGRU: B=8, S=4096, I=512, H=512 (fp32 in/out)
// R12: R8-champion GEMM (128x128, BK=32, 3x24KiB bufs, 2 blocks/CU) with the
//      x fp32->bf16 conversion FUSED via reg-staged A (T14): load fp32 2
//      K-steps ahead -> convert -> swizzled ds_write. B (weights) stays on
//      gload_lds. Kills the 16us cvt x-pass (96 MB intermediate traffic).
//      Wait chain: AWRITE's implicit vmcnt on 2-step-old regs transitively
//      drains B(kt); explicit vmcnt(8/4/0) safety; lgkmcnt(0) before barrier.

typedef __attribute__((ext_vector_type(8))) short short8;   // 8 bf16
typedef __attribute__((ext_vector_type(4))) float f32x4;

#define AS1 __attribute__((address_space(1)))
#define AS3 __attribute__((address_space(3)))

__device__ inline void gload_lds16(const void* g, void* l) {
  __builtin_amdgcn_global_load_lds((AS1 uint32_t*)(g), (AS3 uint32_t*)(l), 16, 0, 0);
}

__device__ inline ushort f2bf(float f) {
  union { __hip_bfloat16 h; ushort u; } v;
  v.h = __float2bfloat16(f);
  return v.u;
}

// ---------------- K0: W fp32 -> bf16 (tiny) ----------------
__global__ void cvt_w(const float* __restrict__ wz, const float* __restrict__ wh,
                      ushort* __restrict__ wzb, ushort* __restrict__ whb) {
  int i = blockIdx.x * 256 + threadIdx.x;     // 65536 float4 per matrix
  float4 a = reinterpret_cast<const float4*>(wz)[i];
  reinterpret_cast<ushort4*>(wzb)[i] =
      make_ushort4(f2bf(a.x), f2bf(a.y), f2bf(a.z), f2bf(a.w));
  float4 b = reinterpret_cast<const float4*>(wh)[i];
  reinterpret_cast<ushort4*>(whb)[i] =
      make_ushort4(f2bf(b.x), f2bf(b.y), f2bf(b.z), f2bf(b.w));
}

// ---------------- K1: GEMM + fused x-cvt + gate + chunk summaries ----------
// grid 1024 (XCD-chunked): tile=(bid&7)*128+(bid>>3); bx=tile>>2 (128-row
// m-tile), by=tile&3 (128-col n-tile of both mats). 4 waves 2x2, wave 64x64.
// LDS: 3 x 24KiB (A 8K | Bz 8K | Bh 8K), BK=32, 16 K-steps, depth-2 pipeline.
// A: reg-staged from fp32 x (convert in-flight), B: gload_lds. Swizzle:
// 16B slot ^= (row>>1)&3, identical on write and read.
__global__ __launch_bounds__(256, 2) void gemm_gate(
    const float* __restrict__ x,     // [32768,512] fp32
    const ushort* __restrict__ wzb,  // [512,512] bf16
    const ushort* __restrict__ whb,  // [512,512] bf16
    const float* __restrict__ b_z,
    const float* __restrict__ b_h,
    uint* __restrict__ ab,           // [32768,512] packed (a,b) bf16
    float2* __restrict__ ABc)        // [8,512,128] chunk summaries (b,h,c)
{
  __shared__ __align__(16) char smem[73728];
  // buffer (24 KiB): A [0,8192) 128x32 bf16, Bz [8192,16384), Bh [16384,24576)

  const int t  = threadIdx.x;
  const int w  = t >> 6;
  const int l  = t & 63;
  const int lm = l & 15;
  const int lk = l >> 4;
  const int wm = w >> 1, wn = w & 1;       // wave: rows wm*64.., cols wn*64..
  const int bid  = blockIdx.x;
  const int tile = (bid & 7) * 128 + (bid >> 3);   // bijective (1024 % 8 == 0)
  const int bx = tile >> 2;                // 0..255
  const int by = tile & 3;                 // 0..3
  const int m0 = bx * 128;
  const int n0 = by * 128;

  const int srow = t >> 2;     // B staging: 0..63 rows per issue
  const int ssl  = t & 3;      // 16B slot within 64B row

  const int arow = t >> 1;             // A staging: row 0..127
  const int asl  = (t & 1) * 2;        // dest slots asl, asl+1
  const int aswz = (arow >> 1) & 3;

  f32x4 acc[2][4][4];
  #pragma unroll
  for (int q = 0; q < 2; ++q)
    #pragma unroll
    for (int m = 0; m < 4; ++m)
      #pragma unroll
      for (int n = 0; n < 4; ++n)
        acc[q][m][n] = (f32x4){0.f, 0.f, 0.f, 0.f};

  float4 arA[4], arB[4];

  auto ALOAD = [&](float4* ar, int kt) {   // 4 vm ops
    #pragma unroll
    for (int d = 0; d < 2; ++d) {
      int s = (asl + d) ^ aswz;            // logical k-slot for dest slot
      const float* p = x + (size_t)(m0 + arow) * 512 + kt * 32 + s * 8;
      ar[2 * d]     = *(const float4*)(p);
      ar[2 * d + 1] = *(const float4*)(p + 4);
    }
  };
  auto AWRITE = [&](int sel, const float4* ar) {   // 2 ds_write_b128
    char* base = smem + sel * 24576;
    #pragma unroll
    for (int d = 0; d < 2; ++d) {
      short8 v;
      v[0] = (short)f2bf(ar[2 * d].x);     v[1] = (short)f2bf(ar[2 * d].y);
      v[2] = (short)f2bf(ar[2 * d].z);     v[3] = (short)f2bf(ar[2 * d].w);
      v[4] = (short)f2bf(ar[2 * d + 1].x); v[5] = (short)f2bf(ar[2 * d + 1].y);
      v[6] = (short)f2bf(ar[2 * d + 1].z); v[7] = (short)f2bf(ar[2 * d + 1].w);
      *(short8*)(base + arow * 64 + (asl + d) * 16) = v;
    }
  };
  auto BDMA = [&](int sel, int kt) {       // 4 vm ops
    char* base = smem + sel * 24576;
    const int k0 = kt * 32;
    #pragma unroll
    for (int j = 0; j < 2; ++j) {
      int row = j * 64 + srow;
      int gs  = ssl ^ ((row >> 1) & 3);
      gload_lds16(wzb + (size_t)(n0 + row) * 512 + k0 + gs * 8,
                  base + 8192 + j * 4096 + w * 1024);
      gload_lds16(whb + (size_t)(n0 + row) * 512 + k0 + gs * 8,
                  base + 16384 + j * 4096 + w * 1024);
    }
  };

#define STEP(KT, ARW, ARL)                                                    \
  {                                                                           \
    if ((KT) < 14) ALOAD(ARL, (KT) + 2);                                      \
    if ((KT) < 15) AWRITE(((KT) + 1) % 3, ARW);                               \
    if ((KT) < 14)       asm volatile("s_waitcnt vmcnt(8)" ::: "memory");     \
    else if ((KT) == 14) asm volatile("s_waitcnt vmcnt(4)" ::: "memory");     \
    else                 asm volatile("s_waitcnt vmcnt(0)" ::: "memory");     \
    asm volatile("s_waitcnt lgkmcnt(0)" ::: "memory");                        \
    __builtin_amdgcn_s_barrier();                                             \
    {                                                                         \
      const char* base = smem + ((KT) % 3) * 24576;                           \
      short8 af[4], bfz[4], bfh[4];                                           \
      _Pragma("unroll") for (int m = 0; m < 4; ++m) {                         \
        int row = wm * 64 + m * 16 + lm;                                      \
        af[m] = *(const short8*)(base + row * 64 +                            \
                                 ((lk ^ ((row >> 1) & 3)) << 4));             \
      }                                                                       \
      _Pragma("unroll") for (int n = 0; n < 4; ++n) {                         \
        int row = wn * 64 + n * 16 + lm;                                      \
        int so  = ((lk ^ ((row >> 1) & 3)) << 4);                             \
        bfz[n] = *(const short8*)(base + 8192  + row * 64 + so);              \
        bfh[n] = *(const short8*)(base + 16384 + row * 64 + so);              \
      }                                                                       \
      __builtin_amdgcn_s_setprio(1);                                          \
      _Pragma("unroll") for (int m = 0; m < 4; ++m)                           \
        _Pragma("unroll") for (int n = 0; n < 4; ++n) {                       \
          acc[0][m][n] = __builtin_amdgcn_mfma_f32_16x16x32_bf16(             \
              af[m], bfz[n], acc[0][m][n], 0, 0, 0);                          \
          acc[1][m][n] = __builtin_amdgcn_mfma_f32_16x16x32_bf16(             \
              af[m], bfh[n], acc[1][m][n], 0, 0, 0);                          \
        }                                                                     \
      __builtin_amdgcn_s_setprio(0);                                          \
    }                                                                         \
    __builtin_amdgcn_s_barrier();                                             \
    if ((KT) < 14) BDMA(((KT) + 2) % 3, (KT) + 2);                            \
  }

  // prologue: A ktile0,1 -> regs; B ktile0,1 -> buf0,1; write A(0) to buf0.
  ALOAD(arA, 0);
  ALOAD(arB, 1);
  BDMA(0, 0);
  BDMA(1, 1);
  AWRITE(0, arA);                                   // implicit vmcnt for arA
  asm volatile("s_waitcnt vmcnt(4)" ::: "memory");  // drain B(0) (keep B(1))
  asm volatile("s_waitcnt lgkmcnt(0)" ::: "memory");
  __builtin_amdgcn_s_barrier();

  STEP(0,  arB, arA) STEP(1,  arA, arB) STEP(2,  arB, arA) STEP(3,  arA, arB)
  STEP(4,  arB, arA) STEP(5,  arA, arB) STEP(6,  arB, arA) STEP(7,  arA, arB)
  STEP(8,  arB, arA) STEP(9,  arA, arB) STEP(10, arB, arA) STEP(11, arA, arB)
  STEP(12, arB, arA) STEP(13, arA, arB) STEP(14, arB, arA) STEP(15, arA, arB)
#undef STEP

  // ---- gate epilogue + fused chunk summaries (R8-verified) ----
  // C layout: row = lk*4 + j (within 16), col = lm (m89-verified).
  #pragma unroll
  for (int n = 0; n < 4; ++n) {
    const int col = n0 + wn * 64 + n * 16 + lm;
    const float bzn = b_z[col];
    const float bhn = b_h[col];
    float av[4][4], bv[4][4];   // [m][j]
    #pragma unroll
    for (int m = 0; m < 4; ++m) {
      #pragma unroll
      for (int j = 0; j < 4; ++j) {
        size_t grow = (size_t)(m0 + wm * 64 + m * 16 + lk * 4 + j);
        float uz = acc[0][m][n][j] + bzn;
        float uh = acc[1][m][n][j] + bhn;
        float z  = 1.f / (1.f + __expf(-uz));
        float a  = 1.f - z;
        float bb = z * uh;
        av[m][j] = a;
        bv[m][j] = bb;
        ab[grow * 512 + col] = (uint)f2bf(a) | ((uint)f2bf(bb) << 16);
      }
    }
    // chunk summaries: wave rows = 2 chunks of 32 (time asc: mm, lk, j).
    #pragma unroll
    for (int cb = 0; cb < 2; ++cb) {
      float At[2], Bt[2];
      #pragma unroll
      for (int mm = 0; mm < 2; ++mm) {
        float A = 1.f, Bv = 0.f;
        #pragma unroll
        for (int j = 0; j < 4; ++j) {
          float a = av[2 * cb + mm][j];
          float b = bv[2 * cb + mm][j];
          A  = a * A;
          Bv = a * Bv + b;
        }
        float Ag = 1.f, Bg = 0.f;
        #pragma unroll
        for (int q = 0; q < 4; ++q) {     // lk-segments in time order
          float Aq = __shfl(A,  lm + 16 * q);
          float Bq = __shfl(Bv, lm + 16 * q);
          Ag = Aq * Ag;
          Bg = Aq * Bg + Bq;
        }
        At[mm] = Ag;
        Bt[mm] = Bg;
      }
      float Achunk = At[1] * At[0];
      float Bchunk = At[1] * Bt[0] + Bt[1];
      if (lk == 0) {
        int bidx = bx >> 5;                       // batch
        int c    = (bx & 31) * 4 + wm * 2 + cb;   // chunk within batch
        ABc[((size_t)bidx * 512 + col) * 128 + c] = make_float2(Achunk, Bchunk);
      }
    }
  }
}

// ---------------- K3: wave-parallel scan over chunk summaries ----------------
__global__ __launch_bounds__(256) void chunk_scan(
    const float2* __restrict__ ABc,   // [8,512,128]
    const float* __restrict__ h0,
    float* __restrict__ Hinit)        // [8,128,512]
{
  __shared__ float sm[128][4];
  const int w = threadIdx.x >> 6, l = threadIdx.x & 63;
  const int b   = blockIdx.x >> 7;
  const int h0g = (blockIdx.x & 127) * 4;
  const int h   = h0g + w;

  const float2* base = ABc + ((size_t)b * 512 + h) * 128;
  float2 s1 = base[l];
  float2 s2 = base[64 + l];

  float A1 = s1.x, B1 = s1.y;
  #pragma unroll
  for (int d = 1; d < 64; d <<= 1) {
    float uA = __shfl_up(A1, d);
    float uB = __shfl_up(B1, d);
    if (l >= d) { B1 = A1 * uB + B1; A1 = A1 * uA; }
  }
  float A2 = s2.x, B2 = s2.y;
  #pragma unroll
  for (int d = 1; d < 64; d <<= 1) {
    float uA = __shfl_up(A2, d);
    float uB = __shfl_up(B2, d);
    if (l >= d) { B2 = A2 * uB + B2; A2 = A2 * uA; }
  }
  float PA = __shfl(A1, 63), PB = __shfl(B1, 63);   // prefix of chunks 0..63
  float FA = A2 * PA;
  float FB = A2 * PB + B2;

  float e1A = __shfl_up(A1, 1), e1B = __shfl_up(B1, 1);
  if (l == 0) { e1A = 1.f; e1B = 0.f; }
  float e2A = __shfl_up(FA, 1), e2B = __shfl_up(FB, 1);
  if (l == 0) { e2A = PA; e2B = PB; }

  float h0v = h0[b * 512 + h];
  sm[l][w]      = e1A * h0v + e1B;
  sm[64 + l][w] = e2A * h0v + e2B;
  __syncthreads();

  const int tt = threadIdx.x;
  if (tt < 128) {
    float4 v = *(const float4*)sm[tt];
    *(float4*)(Hinit + ((size_t)b * 128 + tt) * 512 + h0g) = v;
  }
}

// ---------------- K4: replay each chunk from Hinit, write out ----------------
__global__ __launch_bounds__(256) void scan_write(
    const uint* __restrict__ ab,
    const float* __restrict__ Hinit,
    float* __restrict__ out)
{
  int tid = blockIdx.x * 256 + threadIdx.x;   // 131072
  int cg = tid & 127;            // h-group: h = cg*4 ..
  int c  = (tid >> 7) & 127;
  int b  = tid >> 14;
  const uint4* p = reinterpret_cast<const uint4*>(ab + ((size_t)(b * 4096 + c * 32)) * 512) + cg;
  float4 hv = *reinterpret_cast<const float4*>(Hinit + ((size_t)b * 128 + c) * 512 + cg * 4);
  float4* po = reinterpret_cast<float4*>(out + ((size_t)(b * 4096 + c * 32)) * 512) + cg;
  #pragma unroll 4
  for (int t = 0; t < 32; ++t) {
    uint4 u = p[(size_t)t * 128];
    hv.x = __uint_as_float(u.x << 16) * hv.x + __uint_as_float(u.x & 0xffff0000u);
    hv.y = __uint_as_float(u.y << 16) * hv.y + __uint_as_float(u.y & 0xffff0000u);
    hv.z = __uint_as_float(u.z << 16) * hv.z + __uint_as_float(u.z & 0xffff0000u);
    hv.w = __uint_as_float(u.w << 16) * hv.w + __uint_as_float(u.w & 0xffff0000u);
    po[(size_t)t * 128] = hv;
  }
}

extern "C" void kernel_launch(void* const* d_in, const int* in_sizes, int n_in,
                              void* d_out, int out_size, void* d_ws, size_t ws_size,
                              hipStream_t stream) {
  const float* x   = (const float*)d_in[0];
  const float* h0  = (const float*)d_in[1];
  const float* W_z = (const float*)d_in[2];
  const float* b_z = (const float*)d_in[3];
  const float* W_h = (const float*)d_in[4];
  const float* b_h = (const float*)d_in[5];
  float* out = (float*)d_out;

  char* ws = (char*)d_ws;
  ushort* wzb   = (ushort*)(ws);                  //    524,288 B
  ushort* whb   = (ushort*)(ws + 524288);         //    524,288 B
  uint*   ab    = (uint*)  (ws + 1048576);        // 67,108,864 B
  float2* ABc   = (float2*)(ws + 68157440);       //  4,194,304 B  [8,512,128]
  float*  Hinit = (float*) (ws + 72351744);       //  2,097,152 B  [8,128,512]

  cvt_w<<<256, 256, 0, stream>>>(W_z, W_h, wzb, whb);
  gemm_gate<<<1024, 256, 0, stream>>>(x, wzb, whb, b_z, b_h, ab, ABc);
  chunk_scan<<<1024, 256, 0, stream>>>(ABc, h0, Hinit);
  scan_write<<<512, 256, 0, stream>>>(ab, Hinit, out);
}

// Round 14
// 88.028 us; speedup vs baseline: 1.1181x; 1.0416x over previous
//
#include <hip/hip_runtime.h>
#include <hip/hip_bf16.h>
#include <stdint.h>

// MinGRU: B=8, S=4096, I=512, H=512 (fp32 in/out)
// R13: R8-champion GEMM with x-cvt fused via global_load_lds of FP32 A:
//      A tile = 2 planes x [128 rows x 16 f32] (lo-quads / hi-quads), each
//      plane exactly R8's proven 64B-row 4-slot swizzle (slot ^= (row>>1)&3,
//      measured 0 conflicts). ds_read f32x4 pairs -> f2bf pack -> same MFMA.
//      2 x 32KiB buffers (64 KiB, still 2 blocks/CU per R7), R5's proven
//      2-buffer counted-vmcnt(8) schedule. Kills the 16us x-cvt pass.

typedef __attribute__((ext_vector_type(8))) short short8;   // 8 bf16
typedef __attribute__((ext_vector_type(4))) float f32x4;

#define AS1 __attribute__((address_space(1)))
#define AS3 __attribute__((address_space(3)))

__device__ inline void gload_lds16(const void* g, void* l) {
  __builtin_amdgcn_global_load_lds((AS1 uint32_t*)(g), (AS3 uint32_t*)(l), 16, 0, 0);
}

__device__ inline ushort f2bf(float f) {
  union { __hip_bfloat16 h; ushort u; } v;
  v.h = __float2bfloat16(f);
  return v.u;
}

// ---------------- K0: W fp32 -> bf16 (tiny) ----------------
__global__ void cvt_w(const float* __restrict__ wz, const float* __restrict__ wh,
                      ushort* __restrict__ wzb, ushort* __restrict__ whb) {
  int i = blockIdx.x * 256 + threadIdx.x;     // 65536 float4 per matrix
  float4 a = reinterpret_cast<const float4*>(wz)[i];
  reinterpret_cast<ushort4*>(wzb)[i] =
      make_ushort4(f2bf(a.x), f2bf(a.y), f2bf(a.z), f2bf(a.w));
  float4 b = reinterpret_cast<const float4*>(wh)[i];
  reinterpret_cast<ushort4*>(whb)[i] =
      make_ushort4(f2bf(b.x), f2bf(b.y), f2bf(b.z), f2bf(b.w));
}

// ---------------- K1: GEMM (fp32-A DMA) + gate + chunk summaries ----------
// grid 1024 (XCD-chunked): tile=(bid&7)*128+(bid>>3); bx=tile>>2 (128-row
// m-tile), by=tile&3 (128-col n-tile, both mats). 4 waves 2x2, wave 64x64.
// LDS buffer (32 KiB): A0 [0,8K) A1 [8K,16K) fp32 planes, Bz [16K,24K),
// Bh [24K,32K) bf16. 2 buffers = 64 KiB. BK=32, 16 K-steps.
// Schedule (R5-proven): stage(kt+1) -> vmcnt(8) -> barrier -> reads+MFMA
// -> barrier. All tiles: 64B rows, 4 slots, swizzle slot ^= (row>>1)&3.
__global__ __launch_bounds__(256, 2) void gemm_gate(
    const float* __restrict__ x,     // [32768,512] fp32
    const ushort* __restrict__ wzb,  // [512,512] bf16
    const ushort* __restrict__ whb,  // [512,512] bf16
    const float* __restrict__ b_z,
    const float* __restrict__ b_h,
    uint* __restrict__ ab,           // [32768,512] packed (a,b) bf16
    float2* __restrict__ ABc)        // [8,512,128] chunk summaries (b,h,c)
{
  __shared__ __align__(16) char smem[65536];

  const int t  = threadIdx.x;
  const int w  = t >> 6;
  const int l  = t & 63;
  const int lm = l & 15;
  const int lk = l >> 4;
  const int wm = w >> 1, wn = w & 1;       // wave: rows wm*64.., cols wn*64..
  const int bid  = blockIdx.x;
  const int tile = (bid & 7) * 128 + (bid >> 3);   // bijective (1024 % 8 == 0)
  const int bx = tile >> 2;                // 0..255
  const int by = tile & 3;                 // 0..3
  const int m0 = bx * 128;
  const int n0 = by * 128;

  const int srow = t >> 2;     // staging: 0..63 rows per issue
  const int ssl  = t & 3;      // 16B dest slot within 64B row

  f32x4 acc[2][4][4];
  #pragma unroll
  for (int q = 0; q < 2; ++q)
    #pragma unroll
    for (int m = 0; m < 4; ++m)
      #pragma unroll
      for (int n = 0; n < 4; ++n)
        acc[q][m][n] = (f32x4){0.f, 0.f, 0.f, 0.f};

  // Exactly 8 gload_lds per stage; no other vmcnt ops in the K-loop.
  // A planes: plane p slot s (16B = 4 f32) of row r holds x k-elems
  // [qlog*8 + p*4 .. +3] where qlog = s ^ ((r>>1)&3).
  auto stage = [&](int sel, int kt) {
    char* base = smem + sel * 32768;
    const int k0 = kt * 32;
    #pragma unroll
    for (int j = 0; j < 2; ++j) {
      int row  = j * 64 + srow;
      int sw   = (row >> 1) & 3;
      int qlog = ssl ^ sw;
      const float* xs = x + (size_t)(m0 + row) * 512 + k0 + qlog * 8;
      gload_lds16(xs,     base +        j * 4096 + w * 1024);   // plane0 (lo)
      gload_lds16(xs + 4, base + 8192 + j * 4096 + w * 1024);   // plane1 (hi)
      int gs = ssl ^ sw;
      gload_lds16(wzb + (size_t)(n0 + row) * 512 + k0 + gs * 8,
                  base + 16384 + j * 4096 + w * 1024);
      gload_lds16(whb + (size_t)(n0 + row) * 512 + k0 + gs * 8,
                  base + 24576 + j * 4096 + w * 1024);
    }
  };

  stage(0, 0);                              // 8 outstanding

  #pragma unroll
  for (int kt = 0; kt < 16; ++kt) {
    const int sel = kt & 1;
    if (kt < 15) {
      stage(sel ^ 1, kt + 1);               // 16 outstanding
      asm volatile("s_waitcnt vmcnt(8)" ::: "memory");   // tile kt landed
    } else {
      asm volatile("s_waitcnt vmcnt(0)" ::: "memory");
    }
    __builtin_amdgcn_s_barrier();           // all waves' tile-kt data landed

    const char* base = smem + sel * 32768;
    short8 af[4], bfz[4], bfh[4];
    #pragma unroll
    for (int m = 0; m < 4; ++m) {
      int row = wm * 64 + m * 16 + lm;
      int so  = ((lk ^ ((row >> 1) & 3)) << 4);
      f32x4 lo = *(const f32x4*)(base +        row * 64 + so);
      f32x4 hi = *(const f32x4*)(base + 8192 + row * 64 + so);
      short8 v;
      v[0] = (short)f2bf(lo[0]); v[1] = (short)f2bf(lo[1]);
      v[2] = (short)f2bf(lo[2]); v[3] = (short)f2bf(lo[3]);
      v[4] = (short)f2bf(hi[0]); v[5] = (short)f2bf(hi[1]);
      v[6] = (short)f2bf(hi[2]); v[7] = (short)f2bf(hi[3]);
      af[m] = v;
    }
    #pragma unroll
    for (int n = 0; n < 4; ++n) {
      int row = wn * 64 + n * 16 + lm;
      int so  = ((lk ^ ((row >> 1) & 3)) << 4);
      bfz[n] = *(const short8*)(base + 16384 + row * 64 + so);
      bfh[n] = *(const short8*)(base + 24576 + row * 64 + so);
    }
    __builtin_amdgcn_s_setprio(1);
    #pragma unroll
    for (int m = 0; m < 4; ++m)
      #pragma unroll
      for (int n = 0; n < 4; ++n) {
        acc[0][m][n] = __builtin_amdgcn_mfma_f32_16x16x32_bf16(af[m], bfz[n], acc[0][m][n], 0, 0, 0);
        acc[1][m][n] = __builtin_amdgcn_mfma_f32_16x16x32_bf16(af[m], bfh[n], acc[1][m][n], 0, 0, 0);
      }
    __builtin_amdgcn_s_setprio(0);
    __builtin_amdgcn_s_barrier();           // protect other buffer's reuse
  }

  // ---- gate epilogue + fused chunk summaries (R8-verified) ----
  // C layout: row = lk*4 + j (within 16), col = lm (m89-verified).
  #pragma unroll
  for (int n = 0; n < 4; ++n) {
    const int col = n0 + wn * 64 + n * 16 + lm;
    const float bzn = b_z[col];
    const float bhn = b_h[col];
    float av[4][4], bv[4][4];   // [m][j]
    #pragma unroll
    for (int m = 0; m < 4; ++m) {
      #pragma unroll
      for (int j = 0; j < 4; ++j) {
        size_t grow = (size_t)(m0 + wm * 64 + m * 16 + lk * 4 + j);
        float uz = acc[0][m][n][j] + bzn;
        float uh = acc[1][m][n][j] + bhn;
        float z  = 1.f / (1.f + __expf(-uz));
        float a  = 1.f - z;
        float bb = z * uh;
        av[m][j] = a;
        bv[m][j] = bb;
        ab[grow * 512 + col] = (uint)f2bf(a) | ((uint)f2bf(bb) << 16);
      }
    }
    // chunk summaries: wave rows = 2 chunks of 32 (time asc: mm, lk, j).
    #pragma unroll
    for (int cb = 0; cb < 2; ++cb) {
      float At[2], Bt[2];
      #pragma unroll
      for (int mm = 0; mm < 2; ++mm) {
        float A = 1.f, Bv = 0.f;
        #pragma unroll
        for (int j = 0; j < 4; ++j) {
          float a = av[2 * cb + mm][j];
          float b = bv[2 * cb + mm][j];
          A  = a * A;
          Bv = a * Bv + b;
        }
        float Ag = 1.f, Bg = 0.f;
        #pragma unroll
        for (int q = 0; q < 4; ++q) {     // lk-segments in time order
          float Aq = __shfl(A,  lm + 16 * q);
          float Bq = __shfl(Bv, lm + 16 * q);
          Ag = Aq * Ag;
          Bg = Aq * Bg + Bq;
        }
        At[mm] = Ag;
        Bt[mm] = Bg;
      }
      float Achunk = At[1] * At[0];
      float Bchunk = At[1] * Bt[0] + Bt[1];
      if (lk == 0) {
        int bidx = bx >> 5;                       // batch
        int c    = (bx & 31) * 4 + wm * 2 + cb;   // chunk within batch
        ABc[((size_t)bidx * 512 + col) * 128 + c] = make_float2(Achunk, Bchunk);
      }
    }
  }
}

// ---------------- K3: wave-parallel scan over chunk summaries ----------------
__global__ __launch_bounds__(256) void chunk_scan(
    const float2* __restrict__ ABc,   // [8,512,128]
    const float* __restrict__ h0,
    float* __restrict__ Hinit)        // [8,128,512]
{
  __shared__ float sm[128][4];
  const int w = threadIdx.x >> 6, l = threadIdx.x & 63;
  const int b   = blockIdx.x >> 7;
  const int h0g = (blockIdx.x & 127) * 4;
  const int h   = h0g + w;

  const float2* base = ABc + ((size_t)b * 512 + h) * 128;
  float2 s1 = base[l];
  float2 s2 = base[64 + l];

  float A1 = s1.x, B1 = s1.y;
  #pragma unroll
  for (int d = 1; d < 64; d <<= 1) {
    float uA = __shfl_up(A1, d);
    float uB = __shfl_up(B1, d);
    if (l >= d) { B1 = A1 * uB + B1; A1 = A1 * uA; }
  }
  float A2 = s2.x, B2 = s2.y;
  #pragma unroll
  for (int d = 1; d < 64; d <<= 1) {
    float uA = __shfl_up(A2, d);
    float uB = __shfl_up(B2, d);
    if (l >= d) { B2 = A2 * uB + B2; A2 = A2 * uA; }
  }
  float PA = __shfl(A1, 63), PB = __shfl(B1, 63);   // prefix of chunks 0..63
  float FA = A2 * PA;
  float FB = A2 * PB + B2;

  float e1A = __shfl_up(A1, 1), e1B = __shfl_up(B1, 1);
  if (l == 0) { e1A = 1.f; e1B = 0.f; }
  float e2A = __shfl_up(FA, 1), e2B = __shfl_up(FB, 1);
  if (l == 0) { e2A = PA; e2B = PB; }

  float h0v = h0[b * 512 + h];
  sm[l][w]      = e1A * h0v + e1B;
  sm[64 + l][w] = e2A * h0v + e2B;
  __syncthreads();

  const int tt = threadIdx.x;
  if (tt < 128) {
    float4 v = *(const float4*)sm[tt];
    *(float4*)(Hinit + ((size_t)b * 128 + tt) * 512 + h0g) = v;
  }
}

// ---------------- K4: replay each chunk from Hinit, write out ----------------
__global__ __launch_bounds__(256) void scan_write(
    const uint* __restrict__ ab,
    const float* __restrict__ Hinit,
    float* __restrict__ out)
{
  int tid = blockIdx.x * 256 + threadIdx.x;   // 131072
  int cg = tid & 127;            // h-group: h = cg*4 ..
  int c  = (tid >> 7) & 127;
  int b  = tid >> 14;
  const uint4* p = reinterpret_cast<const uint4*>(ab + ((size_t)(b * 4096 + c * 32)) * 512) + cg;
  float4 hv = *reinterpret_cast<const float4*>(Hinit + ((size_t)b * 128 + c) * 512 + cg * 4);
  float4* po = reinterpret_cast<float4*>(out + ((size_t)(b * 4096 + c * 32)) * 512) + cg;
  #pragma unroll 4
  for (int t = 0; t < 32; ++t) {
    uint4 u = p[(size_t)t * 128];
    hv.x = __uint_as_float(u.x << 16) * hv.x + __uint_as_float(u.x & 0xffff0000u);
    hv.y = __uint_as_float(u.y << 16) * hv.y + __uint_as_float(u.y & 0xffff0000u);
    hv.z = __uint_as_float(u.z << 16) * hv.z + __uint_as_float(u.z & 0xffff0000u);
    hv.w = __uint_as_float(u.w << 16) * hv.w + __uint_as_float(u.w & 0xffff0000u);
    po[(size_t)t * 128] = hv;
  }
}

extern "C" void kernel_launch(void* const* d_in, const int* in_sizes, int n_in,
                              void* d_out, int out_size, void* d_ws, size_t ws_size,
                              hipStream_t stream) {
  const float* x   = (const float*)d_in[0];
  const float* h0  = (const float*)d_in[1];
  const float* W_z = (const float*)d_in[2];
  const float* b_z = (const float*)d_in[3];
  const float* W_h = (const float*)d_in[4];
  const float* b_h = (const float*)d_in[5];
  float* out = (float*)d_out;

  char* ws = (char*)d_ws;
  ushort* wzb   = (ushort*)(ws);                  //    524,288 B
  ushort* whb   = (ushort*)(ws + 524288);         //    524,288 B
  uint*   ab    = (uint*)  (ws + 1048576);        // 67,108,864 B
  float2* ABc   = (float2*)(ws + 68157440);       //  4,194,304 B  [8,512,128]
  float*  Hinit = (float*) (ws + 72351744);       //  2,097,152 B  [8,128,512]

  cvt_w<<<256, 256, 0, stream>>>(W_z, W_h, wzb, whb);
  gemm_gate<<<1024, 256, 0, stream>>>(x, wzb, whb, b_z, b_h, ab, ABc);
  chunk_scan<<<1024, 256, 0, stream>>>(ABc, h0, Hinit);
  scan_write<<<512, 256, 0, stream>>>(ab, Hinit, out);
}

// Round 16
// 86.771 us; speedup vs baseline: 1.1343x; 1.0145x over previous
//
#include <hip/hip_runtime.h>
#include <hip/hip_bf16.h>
#include <stdint.h>

// MinGRU: B=8, S=4096, I=512, H=512 (fp32 in/out)
// R15: R14 with the NT-store compile fix (ext_vector f32x4 instead of
//      HIP float4 for __builtin_nontemporal_store). Content otherwise
//      identical: XCD-aligned consumers (bid&7 = batch = writer XCD),
//      NT out stores, 2-deep prefetch in scan_write.

typedef __attribute__((ext_vector_type(8))) short short8;   // 8 bf16
typedef __attribute__((ext_vector_type(4))) float f32x4;

#define AS1 __attribute__((address_space(1)))
#define AS3 __attribute__((address_space(3)))

__device__ inline void gload_lds16(const void* g, void* l) {
  __builtin_amdgcn_global_load_lds((AS1 uint32_t*)(g), (AS3 uint32_t*)(l), 16, 0, 0);
}

__device__ inline ushort f2bf(float f) {
  union { __hip_bfloat16 h; ushort u; } v;
  v.h = __float2bfloat16(f);
  return v.u;
}

// ---------------- K0: W fp32 -> bf16 (tiny) ----------------
__global__ void cvt_w(const float* __restrict__ wz, const float* __restrict__ wh,
                      ushort* __restrict__ wzb, ushort* __restrict__ whb) {
  int i = blockIdx.x * 256 + threadIdx.x;     // 65536 float4 per matrix
  float4 a = reinterpret_cast<const float4*>(wz)[i];
  reinterpret_cast<ushort4*>(wzb)[i] =
      make_ushort4(f2bf(a.x), f2bf(a.y), f2bf(a.z), f2bf(a.w));
  float4 b = reinterpret_cast<const float4*>(wh)[i];
  reinterpret_cast<ushort4*>(whb)[i] =
      make_ushort4(f2bf(b.x), f2bf(b.y), f2bf(b.z), f2bf(b.w));
}

// ---------------- K1: GEMM (fp32-A DMA) + gate + chunk summaries ----------
// grid 1024 (XCD-chunked): tile=(bid&7)*128+(bid>>3); bx=tile>>2 (128-row
// m-tile), by=tile&3. XCD k => bx in [k*32,(k+1)*32) => batch k exactly.
// LDS buffer (32 KiB): A planes fp32 [0,16K), Bz [16K,24K), Bh [24K,32K).
// 2 buffers, BK=32, counted vmcnt(8), swizzle slot ^= (row>>1)&3.
__global__ __launch_bounds__(256, 2) void gemm_gate(
    const float* __restrict__ x,     // [32768,512] fp32
    const ushort* __restrict__ wzb,  // [512,512] bf16
    const ushort* __restrict__ whb,  // [512,512] bf16
    const float* __restrict__ b_z,
    const float* __restrict__ b_h,
    uint* __restrict__ ab,           // [32768,512] packed (a,b) bf16
    float2* __restrict__ ABc)        // [8,512,128] chunk summaries (b,h,c)
{
  __shared__ __align__(16) char smem[65536];

  const int t  = threadIdx.x;
  const int w  = t >> 6;
  const int l  = t & 63;
  const int lm = l & 15;
  const int lk = l >> 4;
  const int wm = w >> 1, wn = w & 1;       // wave: rows wm*64.., cols wn*64..
  const int bid  = blockIdx.x;
  const int tile = (bid & 7) * 128 + (bid >> 3);   // bijective (1024 % 8 == 0)
  const int bx = tile >> 2;                // 0..255
  const int by = tile & 3;                 // 0..3
  const int m0 = bx * 128;
  const int n0 = by * 128;

  const int srow = t >> 2;     // staging: 0..63 rows per issue
  const int ssl  = t & 3;      // 16B dest slot within 64B row

  f32x4 acc[2][4][4];
  #pragma unroll
  for (int q = 0; q < 2; ++q)
    #pragma unroll
    for (int m = 0; m < 4; ++m)
      #pragma unroll
      for (int n = 0; n < 4; ++n)
        acc[q][m][n] = (f32x4){0.f, 0.f, 0.f, 0.f};

  auto stage = [&](int sel, int kt) {      // exactly 8 gload_lds
    char* base = smem + sel * 32768;
    const int k0 = kt * 32;
    #pragma unroll
    for (int j = 0; j < 2; ++j) {
      int row  = j * 64 + srow;
      int sw   = (row >> 1) & 3;
      int qlog = ssl ^ sw;
      const float* xs = x + (size_t)(m0 + row) * 512 + k0 + qlog * 8;
      gload_lds16(xs,     base +        j * 4096 + w * 1024);   // plane0 (lo)
      gload_lds16(xs + 4, base + 8192 + j * 4096 + w * 1024);   // plane1 (hi)
      gload_lds16(wzb + (size_t)(n0 + row) * 512 + k0 + qlog * 8,
                  base + 16384 + j * 4096 + w * 1024);
      gload_lds16(whb + (size_t)(n0 + row) * 512 + k0 + qlog * 8,
                  base + 24576 + j * 4096 + w * 1024);
    }
  };

  stage(0, 0);                              // 8 outstanding

  #pragma unroll
  for (int kt = 0; kt < 16; ++kt) {
    const int sel = kt & 1;
    if (kt < 15) {
      stage(sel ^ 1, kt + 1);               // 16 outstanding
      asm volatile("s_waitcnt vmcnt(8)" ::: "memory");   // tile kt landed
    } else {
      asm volatile("s_waitcnt vmcnt(0)" ::: "memory");
    }
    __builtin_amdgcn_s_barrier();           // all waves' tile-kt data landed

    const char* base = smem + sel * 32768;
    short8 af[4], bfz[4], bfh[4];
    #pragma unroll
    for (int m = 0; m < 4; ++m) {
      int row = wm * 64 + m * 16 + lm;
      int so  = ((lk ^ ((row >> 1) & 3)) << 4);
      f32x4 lo = *(const f32x4*)(base +        row * 64 + so);
      f32x4 hi = *(const f32x4*)(base + 8192 + row * 64 + so);
      short8 v;
      v[0] = (short)f2bf(lo[0]); v[1] = (short)f2bf(lo[1]);
      v[2] = (short)f2bf(lo[2]); v[3] = (short)f2bf(lo[3]);
      v[4] = (short)f2bf(hi[0]); v[5] = (short)f2bf(hi[1]);
      v[6] = (short)f2bf(hi[2]); v[7] = (short)f2bf(hi[3]);
      af[m] = v;
    }
    #pragma unroll
    for (int n = 0; n < 4; ++n) {
      int row = wn * 64 + n * 16 + lm;
      int so  = ((lk ^ ((row >> 1) & 3)) << 4);
      bfz[n] = *(const short8*)(base + 16384 + row * 64 + so);
      bfh[n] = *(const short8*)(base + 24576 + row * 64 + so);
    }
    __builtin_amdgcn_s_setprio(1);
    #pragma unroll
    for (int m = 0; m < 4; ++m)
      #pragma unroll
      for (int n = 0; n < 4; ++n) {
        acc[0][m][n] = __builtin_amdgcn_mfma_f32_16x16x32_bf16(af[m], bfz[n], acc[0][m][n], 0, 0, 0);
        acc[1][m][n] = __builtin_amdgcn_mfma_f32_16x16x32_bf16(af[m], bfh[n], acc[1][m][n], 0, 0, 0);
      }
    __builtin_amdgcn_s_setprio(0);
    __builtin_amdgcn_s_barrier();           // protect other buffer's reuse
  }

  // ---- gate epilogue + fused chunk summaries (verified) ----
  // C layout: row = lk*4 + j (within 16), col = lm (m89-verified).
  #pragma unroll
  for (int n = 0; n < 4; ++n) {
    const int col = n0 + wn * 64 + n * 16 + lm;
    const float bzn = b_z[col];
    const float bhn = b_h[col];
    float av[4][4], bv[4][4];   // [m][j]
    #pragma unroll
    for (int m = 0; m < 4; ++m) {
      #pragma unroll
      for (int j = 0; j < 4; ++j) {
        size_t grow = (size_t)(m0 + wm * 64 + m * 16 + lk * 4 + j);
        float uz = acc[0][m][n][j] + bzn;
        float uh = acc[1][m][n][j] + bhn;
        float z  = 1.f / (1.f + __expf(-uz));
        float a  = 1.f - z;
        float bb = z * uh;
        av[m][j] = a;
        bv[m][j] = bb;
        ab[grow * 512 + col] = (uint)f2bf(a) | ((uint)f2bf(bb) << 16);
      }
    }
    // chunk summaries: wave rows = 2 chunks of 32 (time asc: mm, lk, j).
    #pragma unroll
    for (int cb = 0; cb < 2; ++cb) {
      float At[2], Bt[2];
      #pragma unroll
      for (int mm = 0; mm < 2; ++mm) {
        float A = 1.f, Bv = 0.f;
        #pragma unroll
        for (int j = 0; j < 4; ++j) {
          float a = av[2 * cb + mm][j];
          float b = bv[2 * cb + mm][j];
          A  = a * A;
          Bv = a * Bv + b;
        }
        float Ag = 1.f, Bg = 0.f;
        #pragma unroll
        for (int q = 0; q < 4; ++q) {     // lk-segments in time order
          float Aq = __shfl(A,  lm + 16 * q);
          float Bq = __shfl(Bv, lm + 16 * q);
          Ag = Aq * Ag;
          Bg = Aq * Bg + Bq;
        }
        At[mm] = Ag;
        Bt[mm] = Bg;
      }
      float Achunk = At[1] * At[0];
      float Bchunk = At[1] * Bt[0] + Bt[1];
      if (lk == 0) {
        int bidx = bx >> 5;                       // batch (== XCD here)
        int c    = (bx & 31) * 4 + wm * 2 + cb;   // chunk within batch
        ABc[((size_t)bidx * 512 + col) * 128 + c] = make_float2(Achunk, Bchunk);
      }
    }
  }
}

// ---------------- K3: wave-parallel scan over chunk summaries ----------------
// XCD-aligned: block bid&7 = batch (matches gemm's writer XCD for ABc).
__global__ __launch_bounds__(256) void chunk_scan(
    const float2* __restrict__ ABc,   // [8,512,128]
    const float* __restrict__ h0,
    float* __restrict__ Hinit)        // [8,128,512]
{
  __shared__ float sm[128][4];
  const int w = threadIdx.x >> 6, l = threadIdx.x & 63;
  const int b   = blockIdx.x & 7;                 // batch == writer XCD
  const int h0g = (blockIdx.x >> 3) * 4;          // 0..508
  const int h   = h0g + w;

  const float2* base = ABc + ((size_t)b * 512 + h) * 128;
  float2 s1 = base[l];
  float2 s2 = base[64 + l];

  float A1 = s1.x, B1 = s1.y;
  #pragma unroll
  for (int d = 1; d < 64; d <<= 1) {
    float uA = __shfl_up(A1, d);
    float uB = __shfl_up(B1, d);
    if (l >= d) { B1 = A1 * uB + B1; A1 = A1 * uA; }
  }
  float A2 = s2.x, B2 = s2.y;
  #pragma unroll
  for (int d = 1; d < 64; d <<= 1) {
    float uA = __shfl_up(A2, d);
    float uB = __shfl_up(B2, d);
    if (l >= d) { B2 = A2 * uB + B2; A2 = A2 * uA; }
  }
  float PA = __shfl(A1, 63), PB = __shfl(B1, 63);   // prefix of chunks 0..63
  float FA = A2 * PA;
  float FB = A2 * PB + B2;

  float e1A = __shfl_up(A1, 1), e1B = __shfl_up(B1, 1);
  if (l == 0) { e1A = 1.f; e1B = 0.f; }
  float e2A = __shfl_up(FA, 1), e2B = __shfl_up(FB, 1);
  if (l == 0) { e2A = PA; e2B = PB; }

  float h0v = h0[b * 512 + h];
  sm[l][w]      = e1A * h0v + e1B;
  sm[64 + l][w] = e2A * h0v + e2B;
  __syncthreads();

  const int tt = threadIdx.x;
  if (tt < 128) {
    float4 v = *(const float4*)sm[tt];
    *(float4*)(Hinit + ((size_t)b * 128 + tt) * 512 + h0g) = v;
  }
}

// ---------------- K4: replay each chunk from Hinit, write out ----------------
// XCD-aligned: block bid&7 = batch -> ab/Hinit reads hit the writer XCD's L2.
// NT stores for out (never re-read; don't evict ab).
__global__ __launch_bounds__(256) void scan_write(
    const uint* __restrict__ ab,
    const float* __restrict__ Hinit,
    float* __restrict__ out)
{
  const int b   = blockIdx.x & 7;                 // batch == writer XCD
  const int idx = (blockIdx.x >> 3) * 256 + threadIdx.x;   // 0..16383
  const int cg  = idx & 127;           // h-group: h = cg*4 ..
  const int c   = idx >> 7;            // chunk 0..127
  const uint4* p = reinterpret_cast<const uint4*>(ab + ((size_t)(b * 4096 + c * 32)) * 512) + cg;
  float4 hv = *reinterpret_cast<const float4*>(Hinit + ((size_t)b * 128 + c) * 512 + cg * 4);
  f32x4* po = reinterpret_cast<f32x4*>(out + ((size_t)(b * 4096 + c * 32)) * 512 + cg * 4);
  uint4 u = p[0];
  #pragma unroll 4
  for (int t = 0; t < 32; ++t) {
    uint4 un = (t < 31) ? p[(size_t)(t + 1) * 128] : u;   // 2-deep prefetch
    hv.x = __uint_as_float(u.x << 16) * hv.x + __uint_as_float(u.x & 0xffff0000u);
    hv.y = __uint_as_float(u.y << 16) * hv.y + __uint_as_float(u.y & 0xffff0000u);
    hv.z = __uint_as_float(u.z << 16) * hv.z + __uint_as_float(u.z & 0xffff0000u);
    hv.w = __uint_as_float(u.w << 16) * hv.w + __uint_as_float(u.w & 0xffff0000u);
    f32x4 vv = {hv.x, hv.y, hv.z, hv.w};
    __builtin_nontemporal_store(vv, po + (size_t)t * 128);
    u = un;
  }
}

extern "C" void kernel_launch(void* const* d_in, const int* in_sizes, int n_in,
                              void* d_out, int out_size, void* d_ws, size_t ws_size,
                              hipStream_t stream) {
  const float* x   = (const float*)d_in[0];
  const float* h0  = (const float*)d_in[1];
  const float* W_z = (const float*)d_in[2];
  const float* b_z = (const float*)d_in[3];
  const float* W_h = (const float*)d_in[4];
  const float* b_h = (const float*)d_in[5];
  float* out = (float*)d_out;

  char* ws = (char*)d_ws;
  ushort* wzb   = (ushort*)(ws);                  //    524,288 B
  ushort* whb   = (ushort*)(ws + 524288);         //    524,288 B
  uint*   ab    = (uint*)  (ws + 1048576);        // 67,108,864 B
  float2* ABc   = (float2*)(ws + 68157440);       //  4,194,304 B  [8,512,128]
  float*  Hinit = (float*) (ws + 72351744);       //  2,097,152 B  [8,128,512]

  cvt_w<<<256, 256, 0, stream>>>(W_z, W_h, wzb, whb);
  gemm_gate<<<1024, 256, 0, stream>>>(x, wzb, whb, b_z, b_h, ab, ABc);
  chunk_scan<<<1024, 256, 0, stream>>>(ABc, h0, Hinit);
  scan_write<<<512, 256, 0, stream>>>(ab, Hinit, out);
}